// Round 2
// baseline (353.732 us; speedup 1.0000x reference)
//
#include <hip/hip_runtime.h>

#define HD 16
#define DHEAD 64
#define DMODEL 1024
#define BB 2
#define SS 2048
#define MTOT (BB*SS)   // 4096
#define LOG2E 1.44269504f

typedef float f32x4 __attribute__((ext_vector_type(4)));
typedef __bf16 bf16x8 __attribute__((ext_vector_type(8)));
typedef __bf16 bf16x4 __attribute__((ext_vector_type(4)));
typedef unsigned short u16x8 __attribute__((ext_vector_type(8)));

__device__ __forceinline__ unsigned short f2bf(float f) {
    unsigned int u = __builtin_bit_cast(unsigned int, f);
    unsigned int r = (u + 0x7fffu + ((u >> 16) & 1u)) >> 16;   // RNE
    return (unsigned short)r;
}

__device__ __forceinline__ bf16x8 ld8(const unsigned short* p) {
    u16x8 v = *reinterpret_cast<const u16x8*>(p);
    return __builtin_bit_cast(bf16x8, v);
}

__device__ __forceinline__ void gload_lds16(const unsigned short* g, unsigned short* l) {
    __builtin_amdgcn_global_load_lds(
        (const __attribute__((address_space(1))) void*)g,
        (__attribute__((address_space(3))) void*)l, 16, 0, 0);
}

// ---------------- fp32 -> bf16 convert ----------------
__global__ __launch_bounds__(256) void cvt_kernel(const float* __restrict__ in,
                                                  unsigned short* __restrict__ out, int n4) {
    int i = blockIdx.x * blockDim.x + threadIdx.x;
    if (i < n4) {
        float4 v = reinterpret_cast<const float4*>(in)[i];
        ushort4 o;
        o.x = f2bf(v.x); o.y = f2bf(v.y); o.z = f2bf(v.z); o.w = f2bf(v.w);
        reinterpret_cast<ushort4*>(out)[i] = o;
    }
}

// ---------------- GEMM core: C[128x128] = A[M,K] * B[N,K]^T ----------------
// LDS tile layout (elements): [kb(4)][row(128)][8], linear so global_load_lds works.
__device__ __forceinline__ void gemm_core(const unsigned short* __restrict__ A,
                                          const unsigned short* __restrict__ Bm,
                                          unsigned short* Als, unsigned short* Bls,
                                          int m0, int n0, int K, f32x4 acc[4][4]) {
    int t    = threadIdx.x;
    int wv   = t >> 6, lane = t & 63;
    int lrow = lane & 15, lgrp = lane >> 4;
    int wr   = wv >> 1, wc = wv & 1;
    int srow = t & 127, skb = t >> 7;   // staging: row, kb-base

    const unsigned short* Ag = A  + (size_t)(m0 + srow) * K + skb * 8;
    const unsigned short* Bg = Bm + (size_t)(n0 + srow) * K + skb * 8;

    for (int k0 = 0; k0 < K; k0 += 32) {
#pragma unroll
        for (int i = 0; i < 2; ++i) {
            gload_lds16(Ag + k0 + i * 16, Als + i * 2048 + wv * 512);
            gload_lds16(Bg + k0 + i * 16, Bls + i * 2048 + wv * 512);
        }
        __syncthreads();   // compiler drains vmcnt(0) before barrier

        bf16x8 af[4], bfr[4];
#pragma unroll
        for (int i = 0; i < 4; ++i) {
            af[i]  = ld8(&Als[lgrp * 1024 + (wr * 64 + i * 16 + lrow) * 8]);
            bfr[i] = ld8(&Bls[lgrp * 1024 + (wc * 64 + i * 16 + lrow) * 8]);
        }
#pragma unroll
        for (int mi = 0; mi < 4; ++mi)
#pragma unroll
            for (int ni = 0; ni < 4; ++ni)
                acc[mi][ni] = __builtin_amdgcn_mfma_f32_16x16x32_bf16(af[mi], bfr[ni], acc[mi][ni], 0, 0, 0);
        __syncthreads();   // protect LDS before next stage
    }
}

// ---------------- QKV projection (grid.z selects Q/K/V) ----------------
__global__ __launch_bounds__(256) void gemm_qkv(
    const unsigned short* __restrict__ xb,
    const unsigned short* __restrict__ Wqb, const unsigned short* __restrict__ Wkb,
    const unsigned short* __restrict__ Wvb,
    const float* __restrict__ bq, const float* __restrict__ bk, const float* __restrict__ bv,
    unsigned short* __restrict__ Qo, unsigned short* __restrict__ Ko, unsigned short* __restrict__ VTo) {
    __shared__ unsigned short Als[4096], Bls[4096];
    int z = blockIdx.z;
    const unsigned short* Bm = (z == 0) ? Wqb : (z == 1) ? Wkb : Wvb;
    const float* bias = (z == 0) ? bq : (z == 1) ? bk : bv;
    int m0 = blockIdx.y * 128, n0 = blockIdx.x * 128;

    f32x4 acc[4][4];
#pragma unroll
    for (int mi = 0; mi < 4; ++mi)
#pragma unroll
        for (int ni = 0; ni < 4; ++ni) acc[mi][ni] = (f32x4){0.f, 0.f, 0.f, 0.f};

    gemm_core(xb, Bm, Als, Bls, m0, n0, DMODEL, acc);

    int t = threadIdx.x, wv = t >> 6, lane = t & 63;
    int lrow = lane & 15, lgrp = lane >> 4;
    int wr = wv >> 1, wc = wv & 1;
    float scale = (z == 0) ? 0.125f : 1.0f;   // fold 1/sqrt(64) into Q

#pragma unroll
    for (int mi = 0; mi < 4; ++mi) {
#pragma unroll
        for (int ni = 0; ni < 4; ++ni) {
            int col = n0 + wc * 64 + ni * 16 + lrow;
            int h = col >> 6, dh = col & 63;
            float bi = bias[col];
#pragma unroll
            for (int r = 0; r < 4; ++r) {
                int row = m0 + wr * 64 + mi * 16 + lgrp * 4 + r;
                int b = row >> 11, s = row & 2047;
                unsigned short v16 = f2bf((acc[mi][ni][r] + bi) * scale);
                if (z == 2)
                    VTo[((size_t)((b * HD + h) * DHEAD + dh)) * SS + s] = v16;       // V transposed [bh][dh][s]
                else {
                    unsigned short* o = (z == 0) ? Qo : Ko;                           // [bh][s][dh]
                    o[((size_t)((b * HD + h) * SS + s)) * DHEAD + dh] = v16;
                }
            }
        }
    }
}

// ---------------- flash attention: swapped QK^T, 4 waves x 16 q-rows, 64-wide KV tiles ----------------
// Per wave: scores computed as mfma(K,Q) -> S^T so each lane holds one q-row's
// scores (q = lane&15, t = (lane>>4)*4 + r + 16*tt). Softmax reductions are
// 15 local ops + 2 shfl_xor. P routed to PV A-fragment layout through a
// wave-private XOR-swizzled LDS tile (no barriers, bank-balanced b64/b128).
__global__ __launch_bounds__(256) void attn_kernel(
    const unsigned short* __restrict__ Qb, const unsigned short* __restrict__ Kb,
    const unsigned short* __restrict__ VTb, unsigned short* __restrict__ ctxo) {
    __shared__ unsigned short Pls[4][1024];   // per-wave 16q x 64t bf16 (2KB), swizzled
    int bh = blockIdx.y;
    int q0 = blockIdx.x * 64;
    int t = threadIdx.x, wv = t >> 6, lane = t & 63;
    int lrow = lane & 15, lgrp = lane >> 4;
    const unsigned short* Qh  = Qb  + (size_t)bh * SS * DHEAD;
    const unsigned short* Kh  = Kb  + (size_t)bh * SS * DHEAD;
    const unsigned short* VTh = VTb + (size_t)bh * DHEAD * SS;
    int qr = q0 + wv * 16;

    // Q fragments (B operand of swapped QK^T), in registers for the whole kernel
    bf16x8 qf0 = ld8(&Qh[(qr + lrow) * DHEAD + lgrp * 8]);
    bf16x8 qf1 = ld8(&Qh[(qr + lrow) * DHEAD + 32 + lgrp * 8]);

    char* pbase = (char*)&Pls[wv][0];
    int swz = (lrow & 7) << 4;   // XOR-swizzle within 128B row

    f32x4 o[4];
#pragma unroll
    for (int d4 = 0; d4 < 4; ++d4) o[d4] = (f32x4){0.f, 0.f, 0.f, 0.f};
    float mrun = 0.f;   // running max for q = lrow (replicated over lgrp); defer-max, THR=8
    float lrun = 0.f;

    for (int t0 = 0; t0 < SS; t0 += 64) {
        f32x4 sc[4];
#pragma unroll
        for (int tt = 0; tt < 4; ++tt) {
            const unsigned short* krow = &Kh[(size_t)(t0 + tt * 16 + lrow) * DHEAD];
            bf16x8 kf0 = ld8(krow + lgrp * 8);
            bf16x8 kf1 = ld8(krow + 32 + lgrp * 8);
            f32x4 s4 = (f32x4){0.f, 0.f, 0.f, 0.f};
            s4 = __builtin_amdgcn_mfma_f32_16x16x32_bf16(kf0, qf0, s4, 0, 0, 0);
            s4 = __builtin_amdgcn_mfma_f32_16x16x32_bf16(kf1, qf1, s4, 0, 0, 0);
            sc[tt] = s4;   // S^T: lane holds S[q=lrow][t = t0 + 16tt + lgrp*4 + r]
        }

        // tile max over 64 t's for this q-row
        float tm = fmaxf(fmaxf(sc[0][0], sc[0][1]), fmaxf(sc[0][2], sc[0][3]));
#pragma unroll
        for (int tt = 1; tt < 4; ++tt)
            tm = fmaxf(tm, fmaxf(fmaxf(sc[tt][0], sc[tt][1]), fmaxf(sc[tt][2], sc[tt][3])));
        tm = fmaxf(tm, __shfl_xor(tm, 16));
        tm = fmaxf(tm, __shfl_xor(tm, 32));

        if (!__all(tm <= mrun + 8.f)) {   // rare: rescale O and l
            float mn = fmaxf(mrun, tm);
            float al = exp2f((mrun - mn) * LOG2E);
            lrun *= al;
            mrun = mn;
#pragma unroll
            for (int r = 0; r < 4; ++r) {
                float alr = __shfl(al, lgrp * 4 + r);   // al for q = lgrp*4+r
                o[0][r] *= alr; o[1][r] *= alr; o[2][r] *= alr; o[3][r] *= alr;
            }
        }

        float ml = mrun * LOG2E;
        float psum = 0.f;
#pragma unroll
        for (int tt = 0; tt < 4; ++tt) {
            float p0 = exp2f(__builtin_fmaf(sc[tt][0], LOG2E, -ml));
            float p1 = exp2f(__builtin_fmaf(sc[tt][1], LOG2E, -ml));
            float p2 = exp2f(__builtin_fmaf(sc[tt][2], LOG2E, -ml));
            float p3 = exp2f(__builtin_fmaf(sc[tt][3], LOG2E, -ml));
            psum += (p0 + p1) + (p2 + p3);
            bf16x4 pk;
            pk[0] = (__bf16)p0; pk[1] = (__bf16)p1; pk[2] = (__bf16)p2; pk[3] = (__bf16)p3;
            // t range 16tt + 4*lgrp .. +3 for row q=lrow
            *reinterpret_cast<bf16x4*>(pbase + ((lrow * 128 + 32 * tt + 8 * lgrp) ^ swz)) = pk;
        }
        psum += __shfl_xor(psum, 16);
        psum += __shfl_xor(psum, 32);
        lrun += psum;

        // PV: A-frag = P[q=lrow][k = 32*ks + lgrp*8 + j] from swizzled LDS
#pragma unroll
        for (int ks = 0; ks < 2; ++ks) {
            bf16x8 pf = *reinterpret_cast<bf16x8*>(pbase + ((lrow * 128 + 64 * ks + 16 * lgrp) ^ swz));
#pragma unroll
            for (int d4 = 0; d4 < 4; ++d4) {
                bf16x8 vf = ld8(&VTh[(size_t)(d4 * 16 + lrow) * SS + t0 + ks * 32 + lgrp * 8]);
                o[d4] = __builtin_amdgcn_mfma_f32_16x16x32_bf16(pf, vf, o[d4], 0, 0, 0);
            }
        }
    }

    int b = bh >> 4, h = bh & 15;
#pragma unroll
    for (int r = 0; r < 4; ++r) {
        float lr = __shfl(lrun, lgrp * 4 + r);   // l for q = lgrp*4+r
        float inv = 1.f / lr;
        int s = qr + lgrp * 4 + r;
        size_t base = ((size_t)(b * SS + s)) * DMODEL + h * DHEAD;
#pragma unroll
        for (int d4 = 0; d4 < 4; ++d4)
            ctxo[base + d4 * 16 + lrow] = f2bf(o[d4][r] * inv);
    }
}

// ---------------- output projection -> fp32 proj ----------------
__global__ __launch_bounds__(256) void gemm_proj(
    const unsigned short* __restrict__ ctxb, const unsigned short* __restrict__ Wdb,
    const float* __restrict__ bd, float* __restrict__ proj) {
    __shared__ unsigned short Als[4096], Bls[4096];
    int m0 = blockIdx.y * 128, n0 = blockIdx.x * 128;
    f32x4 acc[4][4];
#pragma unroll
    for (int mi = 0; mi < 4; ++mi)
#pragma unroll
        for (int ni = 0; ni < 4; ++ni) acc[mi][ni] = (f32x4){0.f, 0.f, 0.f, 0.f};

    gemm_core(ctxb, Wdb, Als, Bls, m0, n0, DMODEL, acc);

    int t = threadIdx.x, wv = t >> 6, lane = t & 63;
    int lrow = lane & 15, lgrp = lane >> 4;
    int wr = wv >> 1, wc = wv & 1;
#pragma unroll
    for (int mi = 0; mi < 4; ++mi)
#pragma unroll
        for (int ni = 0; ni < 4; ++ni) {
            int col = n0 + wc * 64 + ni * 16 + lrow;
            float bi = bd[col];
#pragma unroll
            for (int r = 0; r < 4; ++r) {
                int row = m0 + wr * 64 + mi * 16 + lgrp * 4 + r;
                proj[(size_t)row * DMODEL + col] = acc[mi][ni][r] + bi;
            }
        }
}

// ---------------- LayerNorm over D=1024 ----------------
__global__ __launch_bounds__(256) void ln_kernel(const float* __restrict__ proj,
                                                 const float* __restrict__ g,
                                                 const float* __restrict__ bv,
                                                 float* __restrict__ out) {
    int row = blockIdx.x, t = threadIdx.x;
    float4 v = reinterpret_cast<const float4*>(proj + (size_t)row * DMODEL)[t];
    float s  = v.x + v.y + v.z + v.w;
    float s2 = v.x * v.x + v.y * v.y + v.z * v.z + v.w * v.w;
#pragma unroll
    for (int m = 1; m < 64; m <<= 1) { s += __shfl_xor(s, m); s2 += __shfl_xor(s2, m); }
    __shared__ float red[8];
    int wv = t >> 6, lane = t & 63;
    if (lane == 0) { red[wv] = s; red[wv + 4] = s2; }
    __syncthreads();
    s  = red[0] + red[1] + red[2] + red[3];
    s2 = red[4] + red[5] + red[6] + red[7];
    float mu  = s * (1.f / 1024.f);
    float var = s2 * (1.f / 1024.f) - mu * mu;
    float inv = rsqrtf(var + 1e-12f);
    float4 gv = reinterpret_cast<const float4*>(g)[t];
    float4 bb = reinterpret_cast<const float4*>(bv)[t];
    float4 ov;
    ov.x = (v.x - mu) * inv * gv.x + bb.x;
    ov.y = (v.y - mu) * inv * gv.y + bb.y;
    ov.z = (v.z - mu) * inv * gv.z + bb.z;
    ov.w = (v.w - mu) * inv * gv.w + bb.w;
    reinterpret_cast<float4*>(out + (size_t)row * DMODEL)[t] = ov;
}

extern "C" void kernel_launch(void* const* d_in, const int* in_sizes, int n_in,
                              void* d_out, int out_size, void* d_ws, size_t ws_size,
                              hipStream_t stream) {
    const float* x   = (const float*)d_in[0];
    const float* Wq  = (const float*)d_in[1];
    const float* bq  = (const float*)d_in[2];
    const float* Wk  = (const float*)d_in[3];
    const float* bk  = (const float*)d_in[4];
    const float* Wv  = (const float*)d_in[5];
    const float* bv  = (const float*)d_in[6];
    const float* Wd  = (const float*)d_in[7];
    const float* bd  = (const float*)d_in[8];
    const float* lng = (const float*)d_in[9];
    const float* lnb = (const float*)d_in[10];

    char* ws = (char*)d_ws;
    unsigned short* xb   = (unsigned short*)(ws);                    // 8 MB
    unsigned short* Wqb  = (unsigned short*)(ws + (8u  << 20));      // 2 MB each
    unsigned short* Wkb  = (unsigned short*)(ws + (10u << 20));
    unsigned short* Wvb  = (unsigned short*)(ws + (12u << 20));
    unsigned short* Wdb  = (unsigned short*)(ws + (14u << 20));
    unsigned short* Qb   = (unsigned short*)(ws + (16u << 20));      // 8 MB
    unsigned short* Kb   = (unsigned short*)(ws + (24u << 20));      // 8 MB
    unsigned short* VTb  = (unsigned short*)(ws + (32u << 20));      // 8 MB
    unsigned short* ctxb = (unsigned short*)(ws + (40u << 20));      // 8 MB
    float* proj = (float*)(ws + (16u << 20));  // 16 MB, aliases Q/K (dead after attention)

    cvt_kernel<<<4096, 256, 0, stream>>>(x,  xb,  1048576);
    cvt_kernel<<<1024, 256, 0, stream>>>(Wq, Wqb, 262144);
    cvt_kernel<<<1024, 256, 0, stream>>>(Wk, Wkb, 262144);
    cvt_kernel<<<1024, 256, 0, stream>>>(Wv, Wvb, 262144);
    cvt_kernel<<<1024, 256, 0, stream>>>(Wd, Wdb, 262144);

    gemm_qkv<<<dim3(8, 32, 3), 256, 0, stream>>>(xb, Wqb, Wkb, Wvb, bq, bk, bv, Qb, Kb, VTb);
    attn_kernel<<<dim3(32, 32), 256, 0, stream>>>(Qb, Kb, VTb, ctxb);
    gemm_proj<<<dim3(8, 32), 256, 0, stream>>>(ctxb, Wdb, bd, proj);
    ln_kernel<<<4096, 256, 0, stream>>>(proj, lng, lnb, (float*)d_out);
}

// Round 3
// 195.828 us; speedup vs baseline: 1.8063x; 1.8063x over previous
//
#include <hip/hip_runtime.h>

#define HD 16
#define DHEAD 64
#define DMODEL 1024
#define BB 2
#define SS 2048
#define MTOT (BB*SS)   // 4096
#define LOG2E 1.44269504f

typedef float f32x4 __attribute__((ext_vector_type(4)));
typedef __bf16 bf16x8 __attribute__((ext_vector_type(8)));
typedef __bf16 bf16x4 __attribute__((ext_vector_type(4)));
typedef unsigned short u16x8 __attribute__((ext_vector_type(8)));

__device__ __forceinline__ unsigned short f2bf(float f) {
    unsigned int u = __builtin_bit_cast(unsigned int, f);
    unsigned int r = (u + 0x7fffu + ((u >> 16) & 1u)) >> 16;   // RNE
    return (unsigned short)r;
}

__device__ __forceinline__ bf16x8 ld8(const unsigned short* p) {
    u16x8 v = *reinterpret_cast<const u16x8*>(p);
    return __builtin_bit_cast(bf16x8, v);
}

__device__ __forceinline__ void gload_lds16(const unsigned short* g, unsigned short* l) {
    __builtin_amdgcn_global_load_lds(
        (const __attribute__((address_space(1))) void*)g,
        (__attribute__((address_space(3))) void*)l, 16, 0, 0);
}

__device__ __forceinline__ void gload_lds16b(const char* g, char* l) {
    __builtin_amdgcn_global_load_lds(
        (const __attribute__((address_space(1))) void*)g,
        (__attribute__((address_space(3))) void*)l, 16, 0, 0);
}

// ---------------- fp32 -> bf16 converts ----------------
__global__ __launch_bounds__(256) void cvt_kernel(const float* __restrict__ in,
                                                  unsigned short* __restrict__ out, int n4) {
    int i = blockIdx.x * blockDim.x + threadIdx.x;
    if (i < n4) {
        float4 v = reinterpret_cast<const float4*>(in)[i];
        ushort4 o;
        o.x = f2bf(v.x); o.y = f2bf(v.y); o.z = f2bf(v.z); o.w = f2bf(v.w);
        reinterpret_cast<ushort4*>(out)[i] = o;
    }
}

// 4 weight matrices in one launch (z selects)
__global__ __launch_bounds__(256) void cvtw_kernel(const float* __restrict__ w0, const float* __restrict__ w1,
                                                   const float* __restrict__ w2, const float* __restrict__ w3,
                                                   unsigned short* __restrict__ o0, unsigned short* __restrict__ o1,
                                                   unsigned short* __restrict__ o2, unsigned short* __restrict__ o3) {
    int z = blockIdx.y;
    const float* in = (z == 0) ? w0 : (z == 1) ? w1 : (z == 2) ? w2 : w3;
    unsigned short* out = (z == 0) ? o0 : (z == 1) ? o1 : (z == 2) ? o2 : o3;
    int i = blockIdx.x * blockDim.x + threadIdx.x;
    float4 v = reinterpret_cast<const float4*>(in)[i];
    ushort4 o;
    o.x = f2bf(v.x); o.y = f2bf(v.y); o.z = f2bf(v.z); o.w = f2bf(v.w);
    reinterpret_cast<ushort4*>(out)[i] = o;
}

// ---------------- GEMM core: C[128x128] = A[M,K] * B[N,K]^T ----------------
__device__ __forceinline__ void gemm_core(const unsigned short* __restrict__ A,
                                          const unsigned short* __restrict__ Bm,
                                          unsigned short* Als, unsigned short* Bls,
                                          int m0, int n0, int K, f32x4 acc[4][4]) {
    int t    = threadIdx.x;
    int wv   = t >> 6, lane = t & 63;
    int lrow = lane & 15, lgrp = lane >> 4;
    int wr   = wv >> 1, wc = wv & 1;
    int srow = t & 127, skb = t >> 7;   // staging: row, kb-base

    const unsigned short* Ag = A  + (size_t)(m0 + srow) * K + skb * 8;
    const unsigned short* Bg = Bm + (size_t)(n0 + srow) * K + skb * 8;

    for (int k0 = 0; k0 < K; k0 += 32) {
#pragma unroll
        for (int i = 0; i < 2; ++i) {
            gload_lds16(Ag + k0 + i * 16, Als + i * 2048 + wv * 512);
            gload_lds16(Bg + k0 + i * 16, Bls + i * 2048 + wv * 512);
        }
        __syncthreads();

        bf16x8 af[4], bfr[4];
#pragma unroll
        for (int i = 0; i < 4; ++i) {
            af[i]  = ld8(&Als[lgrp * 1024 + (wr * 64 + i * 16 + lrow) * 8]);
            bfr[i] = ld8(&Bls[lgrp * 1024 + (wc * 64 + i * 16 + lrow) * 8]);
        }
#pragma unroll
        for (int mi = 0; mi < 4; ++mi)
#pragma unroll
            for (int ni = 0; ni < 4; ++ni)
                acc[mi][ni] = __builtin_amdgcn_mfma_f32_16x16x32_bf16(af[mi], bfr[ni], acc[mi][ni], 0, 0, 0);
        __syncthreads();
    }
}

// ---------------- QKV projection (grid.z selects Q/K/V) ----------------
__global__ __launch_bounds__(256) void gemm_qkv(
    const unsigned short* __restrict__ xb,
    const unsigned short* __restrict__ Wqb, const unsigned short* __restrict__ Wkb,
    const unsigned short* __restrict__ Wvb,
    const float* __restrict__ bq, const float* __restrict__ bk, const float* __restrict__ bv,
    unsigned short* __restrict__ Qo, unsigned short* __restrict__ Ko, unsigned short* __restrict__ VTo) {
    __shared__ unsigned short Als[4096], Bls[4096];
    int z = blockIdx.z;
    const unsigned short* Bm = (z == 0) ? Wqb : (z == 1) ? Wkb : Wvb;
    const float* bias = (z == 0) ? bq : (z == 1) ? bk : bv;
    int m0 = blockIdx.y * 128, n0 = blockIdx.x * 128;

    f32x4 acc[4][4];
#pragma unroll
    for (int mi = 0; mi < 4; ++mi)
#pragma unroll
        for (int ni = 0; ni < 4; ++ni) acc[mi][ni] = (f32x4){0.f, 0.f, 0.f, 0.f};

    gemm_core(xb, Bm, Als, Bls, m0, n0, DMODEL, acc);

    int t = threadIdx.x, wv = t >> 6, lane = t & 63;
    int lrow = lane & 15, lgrp = lane >> 4;
    int wr = wv >> 1, wc = wv & 1;
    float scale = (z == 0) ? 0.125f : 1.0f;   // fold 1/sqrt(64) into Q

#pragma unroll
    for (int mi = 0; mi < 4; ++mi) {
#pragma unroll
        for (int ni = 0; ni < 4; ++ni) {
            int col = n0 + wc * 64 + ni * 16 + lrow;
            int h = col >> 6, dh = col & 63;
            float bi = bias[col];
#pragma unroll
            for (int r = 0; r < 4; ++r) {
                int row = m0 + wr * 64 + mi * 16 + lgrp * 4 + r;
                int b = row >> 11, s = row & 2047;
                unsigned short v16 = f2bf((acc[mi][ni][r] + bi) * scale);
                if (z == 2)
                    VTo[((size_t)((b * HD + h) * DHEAD + dh)) * SS + s] = v16;       // V transposed [bh][dh][s]
                else {
                    unsigned short* o = (z == 0) ? Qo : Ko;                           // [bh][s][dh]
                    o[((size_t)((b * HD + h) * SS + s)) * DHEAD + dh] = v16;
                }
            }
        }
    }
}

// ---------------- flash attention ----------------
// Block = 4 waves x 16 q-rows. K/V tiles (64x64 bf16) staged in double-buffered
// LDS via global_load_lds (shared by all 4 waves), issued one tile ahead; one
// barrier per tile (its vmcnt drain is the pipeline wait). LDS tiles are
// XOR-swizzled (byte ^= (row&7)<<4) via pre-swizzled global source so
// ds_read_b128 frag reads are bank-uniform. Swapped QK^T (mfma(K,Q)) keeps a
// full q-row per lane -> softmax is local ops + 2 shfl_xor, defer-max THR=8.
__global__ __launch_bounds__(256) void attn_kernel(
    const unsigned short* __restrict__ Qb, const unsigned short* __restrict__ Kb,
    const unsigned short* __restrict__ VTb, unsigned short* __restrict__ ctxo) {
    __shared__ unsigned short Kls[2][4096];   // 8KB per buf
    __shared__ unsigned short Vls[2][4096];
    __shared__ unsigned short Pls[4][1024];   // per-wave 16q x 64t bf16, swizzled
    int bh = blockIdx.y;
    int q0 = blockIdx.x * 64;
    int t = threadIdx.x, wv = t >> 6, lane = t & 63;
    int lrow = lane & 15, lgrp = lane >> 4;
    const unsigned short* Qh  = Qb  + (size_t)bh * SS * DHEAD;
    const char* Khc  = (const char*)(Kb  + (size_t)bh * SS * DHEAD);
    const char* VThc = (const char*)(VTb + (size_t)bh * DHEAD * SS);
    int qr = q0 + wv * 16;

    // Q fragments (B operand of swapped QK^T), in registers for the whole kernel
    bf16x8 qf0 = ld8(&Qh[(qr + lrow) * DHEAD + lgrp * 8]);
    bf16x8 qf1 = ld8(&Qh[(qr + lrow) * DHEAD + 32 + lgrp * 8]);

    // staging: 512 16B-chunks per matrix per tile; this thread owns chunks t, t+256.
    // chunk c -> LDS linear c*16; logical row=c>>3, colbyte=(c&7)*16; source col
    // pre-swizzled so LDS_phys[row][col ^ ((row&7)<<4)] holds logical col.
    int c0 = t, c1 = t + 256;
    int kr0 = c0 >> 3, cb0 = ((c0 & 7) << 4) ^ ((kr0 & 7) << 4);
    int kr1 = c1 >> 3, cb1 = ((c1 & 7) << 4) ^ ((kr1 & 7) << 4);

    char* pbase = (char*)&Pls[wv][0];
    int swz = (lrow & 7) << 4;   // XOR-swizzle within 128B row

    f32x4 o[4];
#pragma unroll
    for (int d4 = 0; d4 < 4; ++d4) o[d4] = (f32x4){0.f, 0.f, 0.f, 0.f};
    float mrun = 0.f;   // defer-max, THR=8
    float lrun = 0.f;

    auto stage = [&](int buf, int t0) {
        gload_lds16b(Khc + (size_t)(t0 + kr0) * 128 + cb0, (char*)&Kls[buf][0] + c0 * 16);
        gload_lds16b(Khc + (size_t)(t0 + kr1) * 128 + cb1, (char*)&Kls[buf][0] + c1 * 16);
        gload_lds16b(VThc + ((size_t)kr0 * SS + t0) * 2 + cb0, (char*)&Vls[buf][0] + c0 * 16);
        gload_lds16b(VThc + ((size_t)kr1 * SS + t0) * 2 + cb1, (char*)&Vls[buf][0] + c1 * 16);
    };

    stage(0, 0);
    __syncthreads();
    int buf = 0;

    for (int t0 = 0; t0 < SS; t0 += 64) {
        if (t0 + 64 < SS) stage(buf ^ 1, t0 + 64);   // issue next tile early

        const char* kls = (const char*)&Kls[buf][0];
        const char* vls = (const char*)&Vls[buf][0];

        f32x4 sc[4];
        __builtin_amdgcn_s_setprio(1);
#pragma unroll
        for (int tt = 0; tt < 4; ++tt) {
            int row = tt * 16 + lrow;
            bf16x8 kf0 = *reinterpret_cast<const bf16x8*>(kls + row * 128 + ((lgrp * 16) ^ swz));
            bf16x8 kf1 = *reinterpret_cast<const bf16x8*>(kls + row * 128 + ((64 + lgrp * 16) ^ swz));
            f32x4 s4 = (f32x4){0.f, 0.f, 0.f, 0.f};
            s4 = __builtin_amdgcn_mfma_f32_16x16x32_bf16(kf0, qf0, s4, 0, 0, 0);
            s4 = __builtin_amdgcn_mfma_f32_16x16x32_bf16(kf1, qf1, s4, 0, 0, 0);
            sc[tt] = s4;   // S^T: lane holds S[q=lrow][t = t0 + 16tt + lgrp*4 + r]
        }
        __builtin_amdgcn_s_setprio(0);

        // tile max over 64 t's for this q-row
        float tm = fmaxf(fmaxf(sc[0][0], sc[0][1]), fmaxf(sc[0][2], sc[0][3]));
#pragma unroll
        for (int tt = 1; tt < 4; ++tt)
            tm = fmaxf(tm, fmaxf(fmaxf(sc[tt][0], sc[tt][1]), fmaxf(sc[tt][2], sc[tt][3])));
        tm = fmaxf(tm, __shfl_xor(tm, 16));
        tm = fmaxf(tm, __shfl_xor(tm, 32));

        if (!__all(tm <= mrun + 8.f)) {   // rare: rescale O and l
            float mn = fmaxf(mrun, tm);
            float al = exp2f((mrun - mn) * LOG2E);
            lrun *= al;
            mrun = mn;
#pragma unroll
            for (int r = 0; r < 4; ++r) {
                float alr = __shfl(al, lgrp * 4 + r);
                o[0][r] *= alr; o[1][r] *= alr; o[2][r] *= alr; o[3][r] *= alr;
            }
        }

        float ml = mrun * LOG2E;
        float psum = 0.f;
#pragma unroll
        for (int tt = 0; tt < 4; ++tt) {
            float p0 = exp2f(__builtin_fmaf(sc[tt][0], LOG2E, -ml));
            float p1 = exp2f(__builtin_fmaf(sc[tt][1], LOG2E, -ml));
            float p2 = exp2f(__builtin_fmaf(sc[tt][2], LOG2E, -ml));
            float p3 = exp2f(__builtin_fmaf(sc[tt][3], LOG2E, -ml));
            psum += (p0 + p1) + (p2 + p3);
            bf16x4 pk;
            pk[0] = (__bf16)p0; pk[1] = (__bf16)p1; pk[2] = (__bf16)p2; pk[3] = (__bf16)p3;
            *reinterpret_cast<bf16x4*>(pbase + ((lrow * 128 + 32 * tt + 8 * lgrp) ^ swz)) = pk;
        }
        psum += __shfl_xor(psum, 16);
        psum += __shfl_xor(psum, 32);
        lrun += psum;

        // PV: A-frag = P[q=lrow][k], B-frag = V^T from swizzled LDS
        __builtin_amdgcn_s_setprio(1);
#pragma unroll
        for (int ks = 0; ks < 2; ++ks) {
            bf16x8 pf = *reinterpret_cast<bf16x8*>(pbase + ((lrow * 128 + 64 * ks + 16 * lgrp) ^ swz));
#pragma unroll
            for (int d4 = 0; d4 < 4; ++d4) {
                int row = d4 * 16 + lrow;
                bf16x8 vf = *reinterpret_cast<const bf16x8*>(vls + row * 128 + ((ks * 64 + lgrp * 16) ^ swz));
                o[d4] = __builtin_amdgcn_mfma_f32_16x16x32_bf16(pf, vf, o[d4], 0, 0, 0);
            }
        }
        __builtin_amdgcn_s_setprio(0);

        __syncthreads();   // drains vmcnt (next tile staged) + protects buf swap
        buf ^= 1;
    }

    int b = bh >> 4, h = bh & 15;
#pragma unroll
    for (int r = 0; r < 4; ++r) {
        float lr = __shfl(lrun, lgrp * 4 + r);
        float inv = 1.f / lr;
        int s = qr + lgrp * 4 + r;
        size_t base = ((size_t)(b * SS + s)) * DMODEL + h * DHEAD;
#pragma unroll
        for (int d4 = 0; d4 < 4; ++d4)
            ctxo[base + d4 * 16 + lrow] = f2bf(o[d4][r] * inv);
    }
}

// ---------------- output projection -> fp32 proj ----------------
__global__ __launch_bounds__(256) void gemm_proj(
    const unsigned short* __restrict__ ctxb, const unsigned short* __restrict__ Wdb,
    const float* __restrict__ bd, float* __restrict__ proj) {
    __shared__ unsigned short Als[4096], Bls[4096];
    int m0 = blockIdx.y * 128, n0 = blockIdx.x * 128;
    f32x4 acc[4][4];
#pragma unroll
    for (int mi = 0; mi < 4; ++mi)
#pragma unroll
        for (int ni = 0; ni < 4; ++ni) acc[mi][ni] = (f32x4){0.f, 0.f, 0.f, 0.f};

    gemm_core(ctxb, Wdb, Als, Bls, m0, n0, DMODEL, acc);

    int t = threadIdx.x, wv = t >> 6, lane = t & 63;
    int lrow = lane & 15, lgrp = lane >> 4;
    int wr = wv >> 1, wc = wv & 1;
#pragma unroll
    for (int mi = 0; mi < 4; ++mi)
#pragma unroll
        for (int ni = 0; ni < 4; ++ni) {
            int col = n0 + wc * 64 + ni * 16 + lrow;
            float bi = bd[col];
#pragma unroll
            for (int r = 0; r < 4; ++r) {
                int row = m0 + wr * 64 + mi * 16 + lgrp * 4 + r;
                proj[(size_t)row * DMODEL + col] = acc[mi][ni][r] + bi;
            }
        }
}

// ---------------- LayerNorm over D=1024 ----------------
__global__ __launch_bounds__(256) void ln_kernel(const float* __restrict__ proj,
                                                 const float* __restrict__ g,
                                                 const float* __restrict__ bv,
                                                 float* __restrict__ out) {
    int row = blockIdx.x, t = threadIdx.x;
    float4 v = reinterpret_cast<const float4*>(proj + (size_t)row * DMODEL)[t];
    float s  = v.x + v.y + v.z + v.w;
    float s2 = v.x * v.x + v.y * v.y + v.z * v.z + v.w * v.w;
#pragma unroll
    for (int m = 1; m < 64; m <<= 1) { s += __shfl_xor(s, m); s2 += __shfl_xor(s2, m); }
    __shared__ float red[8];
    int wv = t >> 6, lane = t & 63;
    if (lane == 0) { red[wv] = s; red[wv + 4] = s2; }
    __syncthreads();
    s  = red[0] + red[1] + red[2] + red[3];
    s2 = red[4] + red[5] + red[6] + red[7];
    float mu  = s * (1.f / 1024.f);
    float var = s2 * (1.f / 1024.f) - mu * mu;
    float inv = rsqrtf(var + 1e-12f);
    float4 gv = reinterpret_cast<const float4*>(g)[t];
    float4 bb = reinterpret_cast<const float4*>(bv)[t];
    float4 ov;
    ov.x = (v.x - mu) * inv * gv.x + bb.x;
    ov.y = (v.y - mu) * inv * gv.y + bb.y;
    ov.z = (v.z - mu) * inv * gv.z + bb.z;
    ov.w = (v.w - mu) * inv * gv.w + bb.w;
    reinterpret_cast<float4*>(out + (size_t)row * DMODEL)[t] = ov;
}

extern "C" void kernel_launch(void* const* d_in, const int* in_sizes, int n_in,
                              void* d_out, int out_size, void* d_ws, size_t ws_size,
                              hipStream_t stream) {
    const float* x   = (const float*)d_in[0];
    const float* Wq  = (const float*)d_in[1];
    const float* bq  = (const float*)d_in[2];
    const float* Wk  = (const float*)d_in[3];
    const float* bk  = (const float*)d_in[4];
    const float* Wv  = (const float*)d_in[5];
    const float* bv  = (const float*)d_in[6];
    const float* Wd  = (const float*)d_in[7];
    const float* bd  = (const float*)d_in[8];
    const float* lng = (const float*)d_in[9];
    const float* lnb = (const float*)d_in[10];

    char* ws = (char*)d_ws;
    unsigned short* xb   = (unsigned short*)(ws);                    // 8 MB
    unsigned short* Wqb  = (unsigned short*)(ws + (8u  << 20));      // 2 MB each
    unsigned short* Wkb  = (unsigned short*)(ws + (10u << 20));
    unsigned short* Wvb  = (unsigned short*)(ws + (12u << 20));
    unsigned short* Wdb  = (unsigned short*)(ws + (14u << 20));
    unsigned short* Qb   = (unsigned short*)(ws + (16u << 20));      // 8 MB
    unsigned short* Kb   = (unsigned short*)(ws + (24u << 20));      // 8 MB
    unsigned short* VTb  = (unsigned short*)(ws + (32u << 20));      // 8 MB
    unsigned short* ctxb = (unsigned short*)(ws + (40u << 20));      // 8 MB
    float* proj = (float*)(ws + (16u << 20));  // 16 MB, aliases Q/K (dead after attention)

    cvt_kernel<<<4096, 256, 0, stream>>>(x, xb, 1048576);
    cvtw_kernel<<<dim3(1024, 4), 256, 0, stream>>>(Wq, Wk, Wv, Wd, Wqb, Wkb, Wvb, Wdb);

    gemm_qkv<<<dim3(8, 32, 3), 256, 0, stream>>>(xb, Wqb, Wkb, Wvb, bq, bk, bv, Qb, Kb, VTb);
    attn_kernel<<<dim3(32, 32), 256, 0, stream>>>(Qb, Kb, VTb, ctxb);
    gemm_proj<<<dim3(8, 32), 256, 0, stream>>>(ctxb, Wdb, bd, proj);
    ln_kernel<<<4096, 256, 0, stream>>>(proj, lng, lnb, (float*)d_out);
}

// Round 4
// 188.820 us; speedup vs baseline: 1.8734x; 1.0371x over previous
//
#include <hip/hip_runtime.h>

#define HD 16
#define DHEAD 64
#define DMODEL 1024
#define BB 2
#define SS 2048
#define MTOT (BB*SS)   // 4096
#define LOG2E 1.44269504f

typedef float f32x4 __attribute__((ext_vector_type(4)));
typedef __bf16 bf16x8 __attribute__((ext_vector_type(8)));
typedef __bf16 bf16x4 __attribute__((ext_vector_type(4)));
typedef unsigned short u16x8 __attribute__((ext_vector_type(8)));

__device__ __forceinline__ unsigned short f2bf(float f) {
    unsigned int u = __builtin_bit_cast(unsigned int, f);
    unsigned int r = (u + 0x7fffu + ((u >> 16) & 1u)) >> 16;   // RNE
    return (unsigned short)r;
}

__device__ __forceinline__ bf16x8 ld8(const unsigned short* p) {
    u16x8 v = *reinterpret_cast<const u16x8*>(p);
    return __builtin_bit_cast(bf16x8, v);
}

__device__ __forceinline__ void gload_lds16(const unsigned short* g, unsigned short* l) {
    __builtin_amdgcn_global_load_lds(
        (const __attribute__((address_space(1))) void*)g,
        (__attribute__((address_space(3))) void*)l, 16, 0, 0);
}

__device__ __forceinline__ void gload_lds16b(const char* g, char* l) {
    __builtin_amdgcn_global_load_lds(
        (const __attribute__((address_space(1))) void*)g,
        (__attribute__((address_space(3))) void*)l, 16, 0, 0);
}

// ---------------- fp32 -> bf16 converts ----------------
__global__ __launch_bounds__(256) void cvt_kernel(const float* __restrict__ in,
                                                  unsigned short* __restrict__ out, int n4) {
    int i = blockIdx.x * blockDim.x + threadIdx.x;
    if (i < n4) {
        float4 v = reinterpret_cast<const float4*>(in)[i];
        ushort4 o;
        o.x = f2bf(v.x); o.y = f2bf(v.y); o.z = f2bf(v.z); o.w = f2bf(v.w);
        reinterpret_cast<ushort4*>(out)[i] = o;
    }
}

// 4 weight matrices in one launch (y selects)
__global__ __launch_bounds__(256) void cvtw_kernel(const float* __restrict__ w0, const float* __restrict__ w1,
                                                   const float* __restrict__ w2, const float* __restrict__ w3,
                                                   unsigned short* __restrict__ o0, unsigned short* __restrict__ o1,
                                                   unsigned short* __restrict__ o2, unsigned short* __restrict__ o3) {
    int z = blockIdx.y;
    const float* in = (z == 0) ? w0 : (z == 1) ? w1 : (z == 2) ? w2 : w3;
    unsigned short* out = (z == 0) ? o0 : (z == 1) ? o1 : (z == 2) ? o2 : o3;
    int i = blockIdx.x * blockDim.x + threadIdx.x;
    float4 v = reinterpret_cast<const float4*>(in)[i];
    ushort4 o;
    o.x = f2bf(v.x); o.y = f2bf(v.y); o.z = f2bf(v.z); o.w = f2bf(v.w);
    reinterpret_cast<ushort4*>(out)[i] = o;
}

// ---------------- GEMM core: C[128x128] = A[M,K] * B[N,K]^T ----------------
__device__ __forceinline__ void gemm_core(const unsigned short* __restrict__ A,
                                          const unsigned short* __restrict__ Bm,
                                          unsigned short* Als, unsigned short* Bls,
                                          int m0, int n0, int K, f32x4 acc[4][4]) {
    int t    = threadIdx.x;
    int wv   = t >> 6, lane = t & 63;
    int lrow = lane & 15, lgrp = lane >> 4;
    int wr   = wv >> 1, wc = wv & 1;
    int srow = t & 127, skb = t >> 7;   // staging: row, kb-base

    const unsigned short* Ag = A  + (size_t)(m0 + srow) * K + skb * 8;
    const unsigned short* Bg = Bm + (size_t)(n0 + srow) * K + skb * 8;

    for (int k0 = 0; k0 < K; k0 += 32) {
#pragma unroll
        for (int i = 0; i < 2; ++i) {
            gload_lds16(Ag + k0 + i * 16, Als + i * 2048 + wv * 512);
            gload_lds16(Bg + k0 + i * 16, Bls + i * 2048 + wv * 512);
        }
        __syncthreads();

        bf16x8 af[4], bfr[4];
#pragma unroll
        for (int i = 0; i < 4; ++i) {
            af[i]  = ld8(&Als[lgrp * 1024 + (wr * 64 + i * 16 + lrow) * 8]);
            bfr[i] = ld8(&Bls[lgrp * 1024 + (wc * 64 + i * 16 + lrow) * 8]);
        }
#pragma unroll
        for (int mi = 0; mi < 4; ++mi)
#pragma unroll
            for (int ni = 0; ni < 4; ++ni)
                acc[mi][ni] = __builtin_amdgcn_mfma_f32_16x16x32_bf16(af[mi], bfr[ni], acc[mi][ni], 0, 0, 0);
        __syncthreads();
    }
}

// ---------------- QKV projection (grid.z selects Q/K/V) ----------------
__global__ __launch_bounds__(256) void gemm_qkv(
    const unsigned short* __restrict__ xb,
    const unsigned short* __restrict__ Wqb, const unsigned short* __restrict__ Wkb,
    const unsigned short* __restrict__ Wvb,
    const float* __restrict__ bq, const float* __restrict__ bk, const float* __restrict__ bv,
    unsigned short* __restrict__ Qo, unsigned short* __restrict__ Ko, unsigned short* __restrict__ VTo) {
    __shared__ unsigned short Als[4096], Bls[4096];
    int z = blockIdx.z;
    const unsigned short* Bm = (z == 0) ? Wqb : (z == 1) ? Wkb : Wvb;
    const float* bias = (z == 0) ? bq : (z == 1) ? bk : bv;
    int m0 = blockIdx.y * 128, n0 = blockIdx.x * 128;

    f32x4 acc[4][4];
#pragma unroll
    for (int mi = 0; mi < 4; ++mi)
#pragma unroll
        for (int ni = 0; ni < 4; ++ni) acc[mi][ni] = (f32x4){0.f, 0.f, 0.f, 0.f};

    gemm_core(xb, Bm, Als, Bls, m0, n0, DMODEL, acc);

    int t = threadIdx.x, wv = t >> 6, lane = t & 63;
    int lrow = lane & 15, lgrp = lane >> 4;
    int wr = wv >> 1, wc = wv & 1;
    float scale = (z == 0) ? 0.125f : 1.0f;   // fold 1/sqrt(64) into Q

#pragma unroll
    for (int mi = 0; mi < 4; ++mi) {
#pragma unroll
        for (int ni = 0; ni < 4; ++ni) {
            int col = n0 + wc * 64 + ni * 16 + lrow;
            int h = col >> 6, dh = col & 63;
            float bi = bias[col];
#pragma unroll
            for (int r = 0; r < 4; ++r) {
                int row = m0 + wr * 64 + mi * 16 + lgrp * 4 + r;
                int b = row >> 11, s = row & 2047;
                unsigned short v16 = f2bf((acc[mi][ni][r] + bi) * scale);
                if (z == 2)
                    VTo[((size_t)((b * HD + h) * DHEAD + dh)) * SS + s] = v16;       // V transposed [bh][dh][s]
                else {
                    unsigned short* o = (z == 0) ? Qo : Ko;                           // [bh][s][dh]
                    o[((size_t)((b * HD + h) * SS + s)) * DHEAD + dh] = v16;
                }
            }
        }
    }
}

// ---------------- flash attention ----------------
// Block = 4 waves x 16 q-rows. K/V tiles (64x64 bf16) double-buffered in LDS via
// global_load_lds, issued one tile ahead; one barrier per tile. XOR-swizzled LDS
// (pre-swizzled global source). Swapped QK^T -> lane holds one q-row.
// Softmax common path is fully lane-local: per-lane partial row-sum (merged by
// 2 shuffles ONCE at the end), per-lane local max + scalar __any vote for the
// (rare) defer-max rescale. No per-tile cross-lane ops.
__global__ __launch_bounds__(256) void attn_kernel(
    const unsigned short* __restrict__ Qb, const unsigned short* __restrict__ Kb,
    const unsigned short* __restrict__ VTb, unsigned short* __restrict__ ctxo) {
    __shared__ unsigned short Kls[2][4096];   // 8KB per buf
    __shared__ unsigned short Vls[2][4096];
    __shared__ unsigned short Pls[4][1024];   // per-wave 16q x 64t bf16, swizzled
    int bh = blockIdx.y;
    int q0 = blockIdx.x * 64;
    int t = threadIdx.x, wv = t >> 6, lane = t & 63;
    int lrow = lane & 15, lgrp = lane >> 4;
    const unsigned short* Qh  = Qb  + (size_t)bh * SS * DHEAD;
    const char* Khc  = (const char*)(Kb  + (size_t)bh * SS * DHEAD);
    const char* VThc = (const char*)(VTb + (size_t)bh * DHEAD * SS);
    int qr = q0 + wv * 16;

    // Q fragments (B operand of swapped QK^T), in registers for the whole kernel
    bf16x8 qf0 = ld8(&Qh[(qr + lrow) * DHEAD + lgrp * 8]);
    bf16x8 qf1 = ld8(&Qh[(qr + lrow) * DHEAD + 32 + lgrp * 8]);

    // staging: 512 16B-chunks per matrix per tile; this thread owns chunks t, t+256.
    int c0 = t, c1 = t + 256;
    int kr0 = c0 >> 3, cb0 = ((c0 & 7) << 4) ^ ((kr0 & 7) << 4);
    int kr1 = c1 >> 3, cb1 = ((c1 & 7) << 4) ^ ((kr1 & 7) << 4);

    char* pbase = (char*)&Pls[wv][0];
    int swz = (lrow & 7) << 4;   // XOR-swizzle within 128B row

    f32x4 o[4];
#pragma unroll
    for (int d4 = 0; d4 < 4; ++d4) o[d4] = (f32x4){0.f, 0.f, 0.f, 0.f};
    float mrun = 0.f;   // row max estimate (row = lrow), uniform across lgrp; defer-max THR=8
    float lp = 0.f;     // PER-LANE partial row-sum (this lane's 16 t's per tile)

    auto stage = [&](int buf, int t0) {
        gload_lds16b(Khc + (size_t)(t0 + kr0) * 128 + cb0, (char*)&Kls[buf][0] + c0 * 16);
        gload_lds16b(Khc + (size_t)(t0 + kr1) * 128 + cb1, (char*)&Kls[buf][0] + c1 * 16);
        gload_lds16b(VThc + ((size_t)kr0 * SS + t0) * 2 + cb0, (char*)&Vls[buf][0] + c0 * 16);
        gload_lds16b(VThc + ((size_t)kr1 * SS + t0) * 2 + cb1, (char*)&Vls[buf][0] + c1 * 16);
    };

    stage(0, 0);
    __syncthreads();
    int buf = 0;

    for (int t0 = 0; t0 < SS; t0 += 64) {
        if (t0 + 64 < SS) stage(buf ^ 1, t0 + 64);   // issue next tile early

        const char* kls = (const char*)&Kls[buf][0];
        const char* vls = (const char*)&Vls[buf][0];

        f32x4 sc[4];
        __builtin_amdgcn_s_setprio(1);
#pragma unroll
        for (int tt = 0; tt < 4; ++tt) {
            int row = tt * 16 + lrow;
            bf16x8 kf0 = *reinterpret_cast<const bf16x8*>(kls + row * 128 + ((lgrp * 16) ^ swz));
            bf16x8 kf1 = *reinterpret_cast<const bf16x8*>(kls + row * 128 + ((64 + lgrp * 16) ^ swz));
            f32x4 s4 = (f32x4){0.f, 0.f, 0.f, 0.f};
            s4 = __builtin_amdgcn_mfma_f32_16x16x32_bf16(kf0, qf0, s4, 0, 0, 0);
            s4 = __builtin_amdgcn_mfma_f32_16x16x32_bf16(kf1, qf1, s4, 0, 0, 0);
            sc[tt] = s4;   // S^T: lane holds S[q=lrow][t = t0 + 16tt + lgrp*4 + r]
        }
        __builtin_amdgcn_s_setprio(0);

        // per-lane local max over this lane's 16 t's (no cross-lane)
        float lm = fmaxf(fmaxf(sc[0][0], sc[0][1]), fmaxf(sc[0][2], sc[0][3]));
#pragma unroll
        for (int tt = 1; tt < 4; ++tt)
            lm = fmaxf(lm, fmaxf(fmaxf(sc[tt][0], sc[tt][1]), fmaxf(sc[tt][2], sc[tt][3])));

        if (__any(lm > mrun + 8.f)) {   // rare: full cross-lane reduce + rescale
            float tm = fmaxf(lm, __shfl_xor(lm, 16));
            tm = fmaxf(tm, __shfl_xor(tm, 32));      // row-uniform tile max
            float mn = fmaxf(mrun, tm);
            float al = exp2f((mrun - mn) * LOG2E);
            lp *= al;
            mrun = mn;
#pragma unroll
            for (int r = 0; r < 4; ++r) {
                float alr = __shfl(al, lgrp * 4 + r);   // al for output row q = lgrp*4+r
                o[0][r] *= alr; o[1][r] *= alr; o[2][r] *= alr; o[3][r] *= alr;
            }
        }

        float ml = mrun * LOG2E;
#pragma unroll
        for (int tt = 0; tt < 4; ++tt) {
            float p0 = exp2f(__builtin_fmaf(sc[tt][0], LOG2E, -ml));
            float p1 = exp2f(__builtin_fmaf(sc[tt][1], LOG2E, -ml));
            float p2 = exp2f(__builtin_fmaf(sc[tt][2], LOG2E, -ml));
            float p3 = exp2f(__builtin_fmaf(sc[tt][3], LOG2E, -ml));
            lp += (p0 + p1) + (p2 + p3);
            bf16x4 pk;
            pk[0] = (__bf16)p0; pk[1] = (__bf16)p1; pk[2] = (__bf16)p2; pk[3] = (__bf16)p3;
            *reinterpret_cast<bf16x4*>(pbase + ((lrow * 128 + 32 * tt + 8 * lgrp) ^ swz)) = pk;
        }

        // PV: A-frag = P[q=lrow][k], B-frag = V^T from swizzled LDS
        __builtin_amdgcn_s_setprio(1);
#pragma unroll
        for (int ks = 0; ks < 2; ++ks) {
            bf16x8 pf = *reinterpret_cast<bf16x8*>(pbase + ((lrow * 128 + 64 * ks + 16 * lgrp) ^ swz));
#pragma unroll
            for (int d4 = 0; d4 < 4; ++d4) {
                int row = d4 * 16 + lrow;
                bf16x8 vf = *reinterpret_cast<const bf16x8*>(vls + row * 128 + ((ks * 64 + lgrp * 16) ^ swz));
                o[d4] = __builtin_amdgcn_mfma_f32_16x16x32_bf16(pf, vf, o[d4], 0, 0, 0);
            }
        }
        __builtin_amdgcn_s_setprio(0);

        __syncthreads();   // drains vmcnt (next tile staged) + protects buf swap
        buf ^= 1;
    }

    // merge per-lane partials -> full row sums (once)
    lp += __shfl_xor(lp, 16);
    lp += __shfl_xor(lp, 32);   // now row-uniform total for row = lrow

    int b = bh >> 4, h = bh & 15;
#pragma unroll
    for (int r = 0; r < 4; ++r) {
        float lr = __shfl(lp, lgrp * 4 + r);   // total for output row q = lgrp*4+r
        float inv = 1.f / lr;
        int s = qr + lgrp * 4 + r;
        size_t base = ((size_t)(b * SS + s)) * DMODEL + h * DHEAD;
#pragma unroll
        for (int d4 = 0; d4 < 4; ++d4)
            ctxo[base + d4 * 16 + lrow] = f2bf(o[d4][r] * inv);
    }
}

// ---------------- output projection -> fp32 proj (128x64 tile, 512 blocks) ----------------
__global__ __launch_bounds__(256) void gemm_proj(
    const unsigned short* __restrict__ ctxb, const unsigned short* __restrict__ Wdb,
    const float* __restrict__ bd, float* __restrict__ proj) {
    __shared__ unsigned short Als[4096];   // [kb4][128][8]
    __shared__ unsigned short Bls[2048];   // [kb4][64][8]
    int m0 = blockIdx.y * 128, n0 = blockIdx.x * 64;
    int t = threadIdx.x, wv = t >> 6, lane = t & 63;
    int lrow = lane & 15, lgrp = lane >> 4;
    int srow = t & 127, skb = t >> 7;

    const unsigned short* Ag = ctxb + (size_t)(m0 + srow) * DMODEL + skb * 8;
    const unsigned short* Bg = Wdb  + (size_t)(n0 + (t & 63)) * DMODEL + wv * 8;

    f32x4 acc[2][4];
#pragma unroll
    for (int mi = 0; mi < 2; ++mi)
#pragma unroll
        for (int ni = 0; ni < 4; ++ni) acc[mi][ni] = (f32x4){0.f, 0.f, 0.f, 0.f};

    for (int k0 = 0; k0 < DMODEL; k0 += 32) {
#pragma unroll
        for (int i = 0; i < 2; ++i)
            gload_lds16(Ag + k0 + i * 16, Als + i * 2048 + wv * 512);
        gload_lds16(Bg + k0, Bls + wv * 512);
        __syncthreads();

        bf16x8 af[2], bfr[4];
#pragma unroll
        for (int i = 0; i < 2; ++i)
            af[i] = ld8(&Als[lgrp * 1024 + (wv * 32 + i * 16 + lrow) * 8]);
#pragma unroll
        for (int i = 0; i < 4; ++i)
            bfr[i] = ld8(&Bls[lgrp * 512 + (i * 16 + lrow) * 8]);
#pragma unroll
        for (int mi = 0; mi < 2; ++mi)
#pragma unroll
            for (int ni = 0; ni < 4; ++ni)
                acc[mi][ni] = __builtin_amdgcn_mfma_f32_16x16x32_bf16(af[mi], bfr[ni], acc[mi][ni], 0, 0, 0);
        __syncthreads();
    }

#pragma unroll
    for (int mi = 0; mi < 2; ++mi)
#pragma unroll
        for (int ni = 0; ni < 4; ++ni) {
            int col = n0 + ni * 16 + lrow;
            float bi = bd[col];
#pragma unroll
            for (int r = 0; r < 4; ++r) {
                int row = m0 + wv * 32 + mi * 16 + lgrp * 4 + r;
                proj[(size_t)row * DMODEL + col] = acc[mi][ni][r] + bi;
            }
        }
}

// ---------------- LayerNorm over D=1024 ----------------
__global__ __launch_bounds__(256) void ln_kernel(const float* __restrict__ proj,
                                                 const float* __restrict__ g,
                                                 const float* __restrict__ bv,
                                                 float* __restrict__ out) {
    int row = blockIdx.x, t = threadIdx.x;
    float4 v = reinterpret_cast<const float4*>(proj + (size_t)row * DMODEL)[t];
    float s  = v.x + v.y + v.z + v.w;
    float s2 = v.x * v.x + v.y * v.y + v.z * v.z + v.w * v.w;
#pragma unroll
    for (int m = 1; m < 64; m <<= 1) { s += __shfl_xor(s, m); s2 += __shfl_xor(s2, m); }
    __shared__ float red[8];
    int wv = t >> 6, lane = t & 63;
    if (lane == 0) { red[wv] = s; red[wv + 4] = s2; }
    __syncthreads();
    s  = red[0] + red[1] + red[2] + red[3];
    s2 = red[4] + red[5] + red[6] + red[7];
    float mu  = s * (1.f / 1024.f);
    float var = s2 * (1.f / 1024.f) - mu * mu;
    float inv = rsqrtf(var + 1e-12f);
    float4 gv = reinterpret_cast<const float4*>(g)[t];
    float4 bb = reinterpret_cast<const float4*>(bv)[t];
    float4 ov;
    ov.x = (v.x - mu) * inv * gv.x + bb.x;
    ov.y = (v.y - mu) * inv * gv.y + bb.y;
    ov.z = (v.z - mu) * inv * gv.z + bb.z;
    ov.w = (v.w - mu) * inv * gv.w + bb.w;
    reinterpret_cast<float4*>(out + (size_t)row * DMODEL)[t] = ov;
}

extern "C" void kernel_launch(void* const* d_in, const int* in_sizes, int n_in,
                              void* d_out, int out_size, void* d_ws, size_t ws_size,
                              hipStream_t stream) {
    const float* x   = (const float*)d_in[0];
    const float* Wq  = (const float*)d_in[1];
    const float* bq  = (const float*)d_in[2];
    const float* Wk  = (const float*)d_in[3];
    const float* bk  = (const float*)d_in[4];
    const float* Wv  = (const float*)d_in[5];
    const float* bv  = (const float*)d_in[6];
    const float* Wd  = (const float*)d_in[7];
    const float* bd  = (const float*)d_in[8];
    const float* lng = (const float*)d_in[9];
    const float* lnb = (const float*)d_in[10];

    char* ws = (char*)d_ws;
    unsigned short* xb   = (unsigned short*)(ws);                    // 8 MB
    unsigned short* Wqb  = (unsigned short*)(ws + (8u  << 20));      // 2 MB each
    unsigned short* Wkb  = (unsigned short*)(ws + (10u << 20));
    unsigned short* Wvb  = (unsigned short*)(ws + (12u << 20));
    unsigned short* Wdb  = (unsigned short*)(ws + (14u << 20));
    unsigned short* Qb   = (unsigned short*)(ws + (16u << 20));      // 8 MB
    unsigned short* Kb   = (unsigned short*)(ws + (24u << 20));      // 8 MB
    unsigned short* VTb  = (unsigned short*)(ws + (32u << 20));      // 8 MB
    unsigned short* ctxb = (unsigned short*)(ws + (40u << 20));      // 8 MB
    float* proj = (float*)(ws + (16u << 20));  // 16 MB, aliases Q/K (dead after attention)

    cvt_kernel<<<4096, 256, 0, stream>>>(x, xb, 1048576);
    cvtw_kernel<<<dim3(1024, 4), 256, 0, stream>>>(Wq, Wk, Wv, Wd, Wqb, Wkb, Wvb, Wdb);

    gemm_qkv<<<dim3(8, 32, 3), 256, 0, stream>>>(xb, Wqb, Wkb, Wvb, bq, bk, bv, Qb, Kb, VTb);
    attn_kernel<<<dim3(32, 32), 256, 0, stream>>>(Qb, Kb, VTb, ctxb);
    gemm_proj<<<dim3(16, 32), 256, 0, stream>>>(ctxb, Wdb, bd, proj);
    ln_kernel<<<4096, 256, 0, stream>>>(proj, lng, lnb, (float*)d_out);
}